// Round 6
// baseline (91.574 us; speedup 1.0000x reference)
//
#include <hip/hip_runtime.h>
#include <stdint.h>

// Problem constants
#define B_ 131072
#define T_ 8
#define C_ 32
#define H_ 4
#define D_ 8

#define TILES_PER_WAVE 4
#define ROWB 208   // LDS row stride in BYTES: 96 f16 (192B) + 16B pad, 16B-aligned

typedef __fp16   fp16x2 __attribute__((ext_vector_type(2)));   // cvt_pkrtz return type
typedef _Float16 f16x8 __attribute__((ext_vector_type(8)));
typedef float    f32x4 __attribute__((ext_vector_type(4)));

union H2U { fp16x2 h; uint32_t u; };

// f32 pair -> packed f16 (RTZ) via the documented clang builtin (no inline asm)
__device__ inline uint32_t pk(float lo, float hi) {
    H2U t; t.h = __builtin_amdgcn_cvt_pkrtz(lo, hi); return t.u;
}

// One wave = 16 rows (2 causal batches of T=8) per tile iteration.
// QKV is computed TRANSPOSED (qkv^T = W^T * X^T) so each lane's MFMA output
// quad is feature-contiguous -> pack to f16, 6x ds_write_b64 per tile.
// Attention reads q/k/v head-slices as single b128 (8 f16).
// PV accumulates in packed f16 (compiler-generated v_pk_fma_f16); its packed
// output IS the FF f16-MFMA A-fragment. LDS is wave-private: no barriers.
__global__ __launch_bounds__(256, 6) void attn_block_mfma(
    const float* __restrict__ X,
    const float* __restrict__ Wq,
    const float* __restrict__ Wk,
    const float* __restrict__ Wv,
    const float* __restrict__ Wf,
    const float* __restrict__ bfb,
    float* __restrict__ Y)
{
    __shared__ __align__(16) char ldsraw[4][16 * ROWB];   // 13.3 KB/block
    const int wid  = threadIdx.x >> 6;
    const int lane = threadIdx.x & 63;
    const int cc = lane & 15;   // frag row/col low index; attention row t
    const int gg = lane >> 4;   // k-group; attention head
    char* qkv = &ldsraw[wid][0];

    // 1/sqrt(D) * log2(e): exp(x) == exp2(x*log2e), folded into Wq
    const float qscale = 0.35355339059327373f * 1.4426950408889634f;

    // ---------- preamble ----------
    // Transposed-projection A-frags: A[row = feature f][k = c], f = head*8+d.
    // A-frag map: row = lane&15, k = gg*8+j (same map proven in rounds 2/3).
    f16x8 aW[6];   // 0,1=q  2,3=k  4,5=v  (each pair = features 0-15,16-31)
    {
        const float* const Ws[3] = { Wq, Wk, Wv };
        #pragma unroll
        for (int tau = 0; tau < 6; ++tau) {
            const float* Wm = Ws[tau >> 1];
            const int f = (tau & 1) * 16 + cc;      // feature 0..31
            const int head = f >> 3, d = f & 7;
            float fv[8];
            #pragma unroll
            for (int j = 0; j < 8; ++j)
                fv[j] = Wm[head * (C_ * D_) + (gg * 8 + j) * D_ + d];
            if (tau < 2) {
                #pragma unroll
                for (int j = 0; j < 8; ++j) fv[j] *= qscale;
            }
            #pragma unroll
            for (int j = 0; j < 8; ++j) aW[tau][j] = (_Float16)fv[j];
        }
    }
    // FF B-frags: B[k = attn-out feature][col = output col], f16
    f16x8 bF[2];
    {
        #pragma unroll
        for (int tau = 0; tau < 2; ++tau) {
            const int col = tau * 16 + cc;
            #pragma unroll
            for (int j = 0; j < 8; ++j)
                bF[tau][j] = (_Float16)Wf[(gg * 8 + j) * C_ + col];
        }
    }
    // bias for the C-frag-layout store: lane owns output cols cc and cc+16
    const float bias0 = bfb[cc];
    const float bias1 = bfb[cc + 16];

    const int waveGlobal = blockIdx.x * 4 + wid;
    const f32x4 z = { 0.f, 0.f, 0.f, 0.f };

    // prefetch first X fragment (lane: row rowbase+cc, floats gg*8..gg*8+7)
    int rowbase = waveGlobal * (16 * TILES_PER_WAVE);
    const float* xp = X + (size_t)(rowbase + cc) * C_ + gg * 8;
    float4 xa = *(const float4*)xp;
    float4 xb = *(const float4*)(xp + 4);

    #pragma unroll 1
    for (int it = 0; it < TILES_PER_WAVE; ++it) {
        rowbase = waveGlobal * (16 * TILES_PER_WAVE) + it * 16;

        // X^T as B-frag: col = lane&15 (= row idx t), k = gg*8+j (= channel c)
        f16x8 aX;
        aX[0] = (_Float16)xa.x; aX[1] = (_Float16)xa.y;
        aX[2] = (_Float16)xa.z; aX[3] = (_Float16)xa.w;
        aX[4] = (_Float16)xb.x; aX[5] = (_Float16)xb.y;
        aX[6] = (_Float16)xb.z; aX[7] = (_Float16)xb.w;

        // prefetch next tile's X (clamped; hides HBM latency under attention)
        {
            const int itn = (it + 1 < TILES_PER_WAVE) ? it + 1 : it;
            const float* xpn = X + (size_t)(waveGlobal * (16 * TILES_PER_WAVE) + itn * 16 + cc) * C_ + gg * 8;
            xa = *(const float4*)xpn;
            xb = *(const float4*)(xpn + 4);
        }

        // ---- QKV transposed: D[f, t] = sum_c W[c,f] X[t,c]; 6 MFMAs ----
        // D: lane holds rows gg*4+r (features), col cc (= t). Feature quad is
        // contiguous -> pack 2x2 f16 and one ds_write_b64 per tau.
        #pragma unroll
        for (int tau = 0; tau < 6; ++tau) {
            f32x4 cq = __builtin_amdgcn_mfma_f32_16x16x32_f16(aW[tau], aX, z, 0, 0, 0);
            uint2 w2;
            w2.x = pk(cq[0], cq[1]);
            w2.y = pk(cq[2], cq[3]);
            *(uint2*)(qkv + cc * ROWB + (tau * 16 + gg * 4) * 2) = w2;
        }

        // ---- attention: lane = (head=gg, row=cc) ----
        const int tpos = cc & 7, bb = cc >> 3;

        const f16x8 q8 = *(const f16x8*)(qkv + cc * ROWB + gg * 16);
        float qf[8];
        #pragma unroll
        for (int j = 0; j < 8; ++j) qf[j] = (float)q8[j];

        float sc[8];
        #pragma unroll
        for (int s = 0; s < 8; ++s) {
            const f16x8 k8 = *(const f16x8*)(qkv + (bb * 8 + s) * ROWB + 64 + gg * 16);
            float acc = 0.f;
            #pragma unroll
            for (int j = 0; j < 8; ++j) acc = fmaf(qf[j], (float)k8[j], acc);
            sc[s] = (s <= tpos) ? acc : -1.0e30f;
        }
        float m = sc[0];
        #pragma unroll
        for (int s = 1; s < 8; ++s) m = fmaxf(m, sc[s]);
        float e[8], sum = 0.f;
        #pragma unroll
        for (int s = 0; s < 8; ++s) { e[s] = exp2f(sc[s] - m); sum += e[s]; }
        const float winv = 1.0f / sum;   // IEEE divide: safe, once per tile

        // PV in packed f16: o8 = sum_s (ws * v8[s]); compiler -> v_pk_fma_f16
        f16x8 o8 = { (_Float16)0, (_Float16)0, (_Float16)0, (_Float16)0,
                     (_Float16)0, (_Float16)0, (_Float16)0, (_Float16)0 };
        #pragma unroll
        for (int s = 0; s < 8; ++s) {
            const f16x8 v8 = *(const f16x8*)(qkv + (bb * 8 + s) * ROWB + 128 + gg * 16);
            const _Float16 wsh = (_Float16)(e[s] * winv);
            o8 += v8 * wsh;
        }

        // ---- FF: o8 IS the A-frag (row=cc, k=gg*8+j) ----
        const f32x4 y0 = __builtin_amdgcn_mfma_f32_16x16x32_f16(o8, bF[0], z, 0, 0, 0);
        const f32x4 y1 = __builtin_amdgcn_mfma_f32_16x16x32_f16(o8, bF[1], z, 0, 0, 0);

        // ---- bias + ReLU in C-frag layout, direct global stores ----
        // lane owns cols cc (y0) and cc+16 (y1), rows gg*4+r; each store inst
        // covers 4 full 64B segments -> coalesced at line granularity.
        #pragma unroll
        for (int r = 0; r < 4; ++r) {
            float* yp = Y + (size_t)(rowbase + gg * 4 + r) * C_;
            yp[cc]      = fmaxf(y0[r] + bias0, 0.f);
            yp[cc + 16] = fmaxf(y1[r] + bias1, 0.f);
        }
    }
}

extern "C" void kernel_launch(void* const* d_in, const int* in_sizes, int n_in,
                              void* d_out, int out_size, void* d_ws, size_t ws_size,
                              hipStream_t stream)
{
    const float* X  = (const float*)d_in[0];
    const float* Wq = (const float*)d_in[1];
    const float* Wk = (const float*)d_in[2];
    const float* Wv = (const float*)d_in[3];
    const float* Wf = (const float*)d_in[4];
    const float* bf = (const float*)d_in[5];
    float* Y = (float*)d_out;

    const int rows = B_ * T_;                           // 1,048,576
    const int rows_per_block = 4 * TILES_PER_WAVE * 16; // 256
    dim3 grid(rows / rows_per_block), block(256);
    hipLaunchKernelGGL(attn_block_mfma, grid, block, 0, stream,
                       X, Wq, Wk, Wv, Wf, bf, Y);
}

// Round 7
// 91.057 us; speedup vs baseline: 1.0057x; 1.0057x over previous
//
#include <hip/hip_runtime.h>
#include <stdint.h>

// Problem constants
#define B_ 131072
#define T_ 8
#define C_ 32
#define H_ 4
#define D_ 8

#define TILES_PER_WAVE 4
#define ROWB 208   // LDS row stride in BYTES: 96 f16 (192B) + 16B pad, 16B-aligned

typedef __fp16   fp16x2 __attribute__((ext_vector_type(2)));   // cvt_pkrtz return type
typedef _Float16 h16x2  __attribute__((ext_vector_type(2)));
typedef _Float16 f16x8  __attribute__((ext_vector_type(8)));
typedef float    f32x4  __attribute__((ext_vector_type(4)));

union H2U { fp16x2 h; uint32_t u; };
// bitcast view of one 16B LDS chunk: load as uint4 (forces ds_read_b128),
// do math as packed h16x2 (v_pk_*_f16), feed MFMA as f16x8.
union V4  { uint4 u; uint32_t w[4]; f16x8 v8; h16x2 h2[4]; };

// f32 pair -> packed f16 (RTZ), documented clang builtin (no inline asm)
__device__ inline uint32_t pk(float lo, float hi) {
    H2U t; t.h = __builtin_amdgcn_cvt_pkrtz(lo, hi); return t.u;
}

// One wave = 16 rows (2 causal batches of T=8) per tile iteration.
// QKV computed TRANSPOSED (qkv^T = W^T * X^T): lane's MFMA quad is
// feature-contiguous -> pack f16, 6x ds_write_b64 per tile.
// ALL LDS reads are uint4 (ds_read_b128) — never deref f16 vectors from
// memory (round-6 lesson: that scalarizes to ds_read_u16 x8).
// Attention dot/PV in packed h16x2 register math; PV output IS the FF
// f16-MFMA A-fragment. LDS is wave-private: no barriers.
__global__ __launch_bounds__(256, 6) void attn_block_mfma(
    const float* __restrict__ X,
    const float* __restrict__ Wq,
    const float* __restrict__ Wk,
    const float* __restrict__ Wv,
    const float* __restrict__ Wf,
    const float* __restrict__ bfb,
    float* __restrict__ Y)
{
    __shared__ __align__(16) char ldsraw[4][16 * ROWB];   // 13.3 KB/block
    const int wid  = threadIdx.x >> 6;
    const int lane = threadIdx.x & 63;
    const int cc = lane & 15;   // frag row/col low index; attention row t
    const int gg = lane >> 4;   // k-group; attention head
    char* qkv = &ldsraw[wid][0];

    // 1/sqrt(D) * log2(e): exp(x) == exp2(x*log2e), folded into Wq
    const float qscale = 0.35355339059327373f * 1.4426950408889634f;

    // ---------- preamble ----------
    // Transposed-projection A-frags: A[row = feature f][k = c], f = head*8+d.
    // A-frag map: row = lane&15, k = gg*8+j (proven rounds 2/3/6).
    f16x8 aW[6];   // 0,1=q  2,3=k  4,5=v  (each pair = features 0-15,16-31)
    {
        const float* const Ws[3] = { Wq, Wk, Wv };
        #pragma unroll
        for (int tau = 0; tau < 6; ++tau) {
            const float* Wm = Ws[tau >> 1];
            const int f = (tau & 1) * 16 + cc;      // feature 0..31
            const int head = f >> 3, d = f & 7;
            float fv[8];
            #pragma unroll
            for (int j = 0; j < 8; ++j)
                fv[j] = Wm[head * (C_ * D_) + (gg * 8 + j) * D_ + d];
            if (tau < 2) {
                #pragma unroll
                for (int j = 0; j < 8; ++j) fv[j] *= qscale;
            }
            #pragma unroll
            for (int j = 0; j < 8; ++j) aW[tau][j] = (_Float16)fv[j];
        }
    }
    // FF B-frags: B[k = attn-out feature][col = output col], f16
    f16x8 bF[2];
    {
        #pragma unroll
        for (int tau = 0; tau < 2; ++tau) {
            const int col = tau * 16 + cc;
            #pragma unroll
            for (int j = 0; j < 8; ++j)
                bF[tau][j] = (_Float16)Wf[(gg * 8 + j) * C_ + col];
        }
    }
    // bias for the C-frag-layout store: lane owns output cols cc and cc+16
    const float bias0 = bfb[cc];
    const float bias1 = bfb[cc + 16];

    const int waveGlobal = blockIdx.x * 4 + wid;
    const f32x4 z = { 0.f, 0.f, 0.f, 0.f };

    // prefetch first X fragment (lane: row rowbase+cc, floats gg*8..gg*8+7)
    int rowbase = waveGlobal * (16 * TILES_PER_WAVE);
    const float* xp = X + (size_t)(rowbase + cc) * C_ + gg * 8;
    float4 xa = *(const float4*)xp;
    float4 xb = *(const float4*)(xp + 4);

    #pragma unroll 1
    for (int it = 0; it < TILES_PER_WAVE; ++it) {
        rowbase = waveGlobal * (16 * TILES_PER_WAVE) + it * 16;

        // X^T as B-frag: col = lane&15 (= row t), k = gg*8+j (= channel c)
        V4 ax;
        ax.w[0] = pk(xa.x, xa.y);
        ax.w[1] = pk(xa.z, xa.w);
        ax.w[2] = pk(xb.x, xb.y);
        ax.w[3] = pk(xb.z, xb.w);

        // prefetch next tile's X (clamped; hides HBM latency under attention)
        {
            const int itn = (it + 1 < TILES_PER_WAVE) ? it + 1 : it;
            const float* xpn = X + (size_t)(waveGlobal * (16 * TILES_PER_WAVE) + itn * 16 + cc) * C_ + gg * 8;
            xa = *(const float4*)xpn;
            xb = *(const float4*)(xpn + 4);
        }

        // ---- QKV transposed: D[f, t] = sum_c W[c,f] X[t,c]; 6 MFMAs ----
        // D: lane holds rows gg*4+r (features), col cc (= t). Feature quad is
        // contiguous -> pack 2x2 f16, one ds_write_b64 per tau.
        #pragma unroll
        for (int tau = 0; tau < 6; ++tau) {
            f32x4 cq = __builtin_amdgcn_mfma_f32_16x16x32_f16(aW[tau], ax.v8, z, 0, 0, 0);
            uint2 w2;
            w2.x = pk(cq[0], cq[1]);
            w2.y = pk(cq[2], cq[3]);
            *(uint2*)(qkv + cc * ROWB + (tau * 16 + gg * 4) * 2) = w2;
        }

        // ---- attention: lane = (head=gg, row=cc) ----
        const int tpos = cc & 7, bb = cc >> 3;

        V4 q;  q.u = *(const uint4*)(qkv + cc * ROWB + gg * 16);   // 1x b128

        float sc[8];
        #pragma unroll
        for (int s = 0; s < 8; ++s) {
            V4 k;  k.u = *(const uint4*)(qkv + (bb * 8 + s) * ROWB + 64 + gg * 16);
            h16x2 a = q.h2[0] * k.h2[0];          // v_pk_mul_f16
            a += q.h2[1] * k.h2[1];               // v_pk_fma_f16
            a += q.h2[2] * k.h2[2];
            a += q.h2[3] * k.h2[3];
            const float dot = (float)a[0] + (float)a[1];
            sc[s] = (s <= tpos) ? dot : -1.0e30f;
        }
        float m = sc[0];
        #pragma unroll
        for (int s = 1; s < 8; ++s) m = fmaxf(m, sc[s]);
        float e[8], sum = 0.f;
        #pragma unroll
        for (int s = 0; s < 8; ++s) { e[s] = exp2f(sc[s] - m); sum += e[s]; }
        const float winv = 1.0f / sum;

        // PV in packed h16x2 register math (v_pk_fma_f16)
        h16x2 o0 = { (_Float16)0, (_Float16)0 };
        h16x2 o1 = o0, o2 = o0, o3 = o0;
        #pragma unroll
        for (int s = 0; s < 8; ++s) {
            V4 v;  v.u = *(const uint4*)(qkv + (bb * 8 + s) * ROWB + 128 + gg * 16);
            const _Float16 wh = (_Float16)(e[s] * winv);
            const h16x2 w2 = { wh, wh };
            o0 += w2 * v.h2[0];
            o1 += w2 * v.h2[1];
            o2 += w2 * v.h2[2];
            o3 += w2 * v.h2[3];
        }

        // ---- FF: PV output IS the A-frag (row=cc, k=gg*8+j) ----
        V4 ov;
        ov.h2[0] = o0; ov.h2[1] = o1; ov.h2[2] = o2; ov.h2[3] = o3;

        const f32x4 y0 = __builtin_amdgcn_mfma_f32_16x16x32_f16(ov.v8, bF[0], z, 0, 0, 0);
        const f32x4 y1 = __builtin_amdgcn_mfma_f32_16x16x32_f16(ov.v8, bF[1], z, 0, 0, 0);

        // ---- bias + ReLU in C-frag layout, direct global stores ----
        // lane owns cols cc (y0) and cc+16 (y1), rows gg*4+r; each store inst
        // covers 4 full 64B segments -> coalesced at line granularity.
        #pragma unroll
        for (int r = 0; r < 4; ++r) {
            float* yp = Y + (size_t)(rowbase + gg * 4 + r) * C_;
            yp[cc]      = fmaxf(y0[r] + bias0, 0.f);
            yp[cc + 16] = fmaxf(y1[r] + bias1, 0.f);
        }
    }
}

extern "C" void kernel_launch(void* const* d_in, const int* in_sizes, int n_in,
                              void* d_out, int out_size, void* d_ws, size_t ws_size,
                              hipStream_t stream)
{
    const float* X  = (const float*)d_in[0];
    const float* Wq = (const float*)d_in[1];
    const float* Wk = (const float*)d_in[2];
    const float* Wv = (const float*)d_in[3];
    const float* Wf = (const float*)d_in[4];
    const float* bf = (const float*)d_in[5];
    float* Y = (float*)d_out;

    const int rows = B_ * T_;                           // 1,048,576
    const int rows_per_block = 4 * TILES_PER_WAVE * 16; // 256
    dim3 grid(rows / rows_per_block), block(256);
    hipLaunchKernelGGL(attn_block_mfma, grid, block, 0, stream,
                       X, Wq, Wk, Wv, Wf, bf, Y);
}

// Round 8
// 73.331 us; speedup vs baseline: 1.2488x; 1.2417x over previous
//
#include <hip/hip_runtime.h>
#include <stdint.h>

// Problem constants
#define B_ 131072
#define T_ 8
#define C_ 32
#define H_ 4
#define D_ 8

#define TILES_PER_WAVE 4
// Per-wave LDS slab (bytes): Q f32 [16 rows][stride 36 dw =144B] = 2304
//                            K_T f16 [32 rows][32B] = 1024, V_T same = 1024
#define QOFF 0
#define KOFF 2304
#define VOFF 3328
#define WAVE_LDS 4352   // 17.4 KB/block -> 8 blocks/CU (LDS no longer binding)

typedef _Float16 h16x2 __attribute__((ext_vector_type(2)));
typedef _Float16 f16x8 __attribute__((ext_vector_type(8)));
typedef float    f32x4 __attribute__((ext_vector_type(4)));
typedef __fp16   fp16x2 __attribute__((ext_vector_type(2)));  // cvt_pkrtz ret type

union H2U { fp16x2 h; uint32_t u; };       // pack 2 f32 -> 1 dword of f16
union HW  { uint32_t u; h16x2 h; };        // dword <-> f16 pair (const-indexed)
union F8U { f16x8 v; uint32_t u[4]; };     // A-frag build (R3-proven pattern)

__device__ inline uint32_t pk(float lo, float hi) {
    H2U t; t.h = __builtin_amdgcn_cvt_pkrtz(lo, hi); return t.u;
}
__device__ inline h16x2 bch(uint32_t x) { HW t; t.u = x; return t.h; }

// One wave = 16 rows (2 causal batches of T=8) per tile. R3 orientation
// (A = X-rows, B = weights; C-frag row=gg*4+r, col=tau*16+cc — proven).
// K,V leave the MFMA as 4-consecutive-s quads per lane -> packed IN-LANE to
// f16 and stored feature-major K_T[f][s] (2 b64 writes each). Row permute
// p(f)=((f&7)<<2)|(f>>3) with 32B rows makes the 8 b128 k-reads and 8 v-reads
// per lane hit 64 distinct bank slots (conflict-free). Q stays f32 (R3 path).
// LDS is wave-private: no barriers anywhere.
__global__ __launch_bounds__(256, 8) void attn_block_mfma(
    const float* __restrict__ X,
    const float* __restrict__ Wq,
    const float* __restrict__ Wk,
    const float* __restrict__ Wv,
    const float* __restrict__ Wf,
    const float* __restrict__ bfb,
    float* __restrict__ Y)
{
    __shared__ __align__(16) char ldsraw[4][WAVE_LDS];
    const int wid  = threadIdx.x >> 6;
    const int lane = threadIdx.x & 63;
    const int cc = lane & 15;   // C-frag col; attention row t
    const int gg = lane >> 4;   // k-group; attention head
    char*  base = &ldsraw[wid][0];
    float* qb = (float*)(base + QOFF);
    char*  kb = base + KOFF;
    char*  vb = base + VOFF;

    const float qscale = 0.35355339059327373f;  // 1/sqrt(D), folded into Wq

    // ---------- preamble: weight B-frags (f16), R3-proven index math ----------
    // B-frag: col = lane&15, k = gg*8+j
    f16x8 bW[6];   // 0,1=q  2,3=k  4,5=v
    {
        const float* const Ws[3] = { Wq, Wk, Wv };
        #pragma unroll
        for (int tau = 0; tau < 6; ++tau) {
            const float* Wm = Ws[tau >> 1];
            const int col = (tau & 1) * 16 + cc;
            const int head = col >> 3, d = col & 7;
            #pragma unroll
            for (int j = 0; j < 8; ++j) {
                float f = Wm[head * (C_ * D_) + (gg * 8 + j) * D_ + d];
                if (tau < 2) f *= qscale;
                bW[tau][j] = (_Float16)f;
            }
        }
    }
    f16x8 bF[2];   // FF weights
    {
        #pragma unroll
        for (int tau = 0; tau < 2; ++tau) {
            const int col = tau * 16 + cc;
            #pragma unroll
            for (int j = 0; j < 8; ++j)
                bF[tau][j] = (_Float16)Wf[(gg * 8 + j) * C_ + col];
        }
    }
    const float bias0 = bfb[cc];
    const float bias1 = bfb[cc + 16];

    const int waveGlobal = blockIdx.x * 4 + wid;
    const f32x4 z = { 0.f, 0.f, 0.f, 0.f };

    // prefetch first X fragment (lane: row rowbase+cc, floats gg*8..+7)
    int rowbase = waveGlobal * (16 * TILES_PER_WAVE);
    const float* xp = X + (size_t)(rowbase + cc) * C_ + gg * 8;
    float4 xa = *(const float4*)xp;
    float4 xb = *(const float4*)(xp + 4);

    #pragma unroll 1
    for (int it = 0; it < TILES_PER_WAVE; ++it) {
        rowbase = waveGlobal * (16 * TILES_PER_WAVE) + it * 16;

        // A-frag from X (row = lane&15, k = gg*8+j)
        f16x8 aX;
        aX[0] = (_Float16)xa.x; aX[1] = (_Float16)xa.y;
        aX[2] = (_Float16)xa.z; aX[3] = (_Float16)xa.w;
        aX[4] = (_Float16)xb.x; aX[5] = (_Float16)xb.y;
        aX[6] = (_Float16)xb.z; aX[7] = (_Float16)xb.w;

        // prefetch next tile's X (clamped; hides HBM latency under attention)
        {
            const int itn = (it + 1 < TILES_PER_WAVE) ? it + 1 : it;
            const float* xpn = X + (size_t)(waveGlobal * (16 * TILES_PER_WAVE) + itn * 16 + cc) * C_ + gg * 8;
            xa = *(const float4*)xpn;
            xb = *(const float4*)(xpn + 4);
        }

        // ---- QKV: 6 MFMAs (R3 orientation). C-frag: row gg*4+r, col tau*16+cc
        f32x4 cq[6];
        #pragma unroll
        for (int tau = 0; tau < 6; ++tau)
            cq[tau] = __builtin_amdgcn_mfma_f32_16x16x32_f16(aX, bW[tau], z, 0, 0, 0);

        // Q -> f32 LDS, stride 36 dwords (R3-proven 2-way banks)
        #pragma unroll
        for (int tau = 0; tau < 2; ++tau)
            #pragma unroll
            for (int r = 0; r < 4; ++r)
                qb[(gg * 4 + r) * 36 + tau * 16 + cc] = cq[tau][r];

        // K,V -> packed f16, feature-major, permuted rows. Lane's 4 values are
        // s = gg*4+0..3 of feature f = (tau&1)*16+cc -> one b64 write.
        #pragma unroll
        for (int tau = 2; tau < 6; ++tau) {
            char* dst = (tau < 4) ? kb : vb;
            const int p = ((cc & 7) << 2) | ((cc >> 3) + (tau & 1) * 2);
            uint2 w2;
            w2.x = pk(cq[tau][0], cq[tau][1]);
            w2.y = pk(cq[tau][2], cq[tau][3]);
            *(uint2*)(dst + p * 32 + gg * 8) = w2;
        }

        // ---- attention: lane = (head=gg, row=cc) ----
        const int tpos = cc & 7, bb = cc >> 3;

        const float4 qa = *(const float4*)(qb + cc * 36 + gg * 8);
        const float4 qv = *(const float4*)(qb + cc * 36 + gg * 8 + 4);
        uint32_t qp[8];
        qp[0] = pk(qa.x, qa.x); qp[1] = pk(qa.y, qa.y);
        qp[2] = pk(qa.z, qa.z); qp[3] = pk(qa.w, qa.w);
        qp[4] = pk(qv.x, qv.x); qp[5] = pk(qv.y, qv.y);
        qp[6] = pk(qv.z, qv.z); qp[7] = pk(qv.w, qv.w);

        // scores: sc2[sp] = sum_f q_f * K_T[f][2sp..2sp+1]  (f16 accum; scores
        // are O(0.01) for this data -> f16 error ~1e-5, harmless)
        h16x2 s01 = { (_Float16)0, (_Float16)0 };
        h16x2 s23 = s01, s45 = s01, s67 = s01;
        #pragma unroll
        for (int j = 0; j < 8; ++j) {
            // K_T row for f = gg*8+j is p = (j<<2)|gg ; bytes bb*16..+15 = 8 s
            const uint4 ku = *(const uint4*)(kb + (((j << 2) | gg) * 32) + bb * 16);
            const h16x2 qj = bch(qp[j]);
            s01 += qj * bch(ku.x);
            s23 += qj * bch(ku.y);
            s45 += qj * bch(ku.z);
            s67 += qj * bch(ku.w);
        }
        float sc[8];
        sc[0] = (float)s01[0]; sc[1] = (float)s01[1];
        sc[2] = (float)s23[0]; sc[3] = (float)s23[1];
        sc[4] = (float)s45[0]; sc[5] = (float)s45[1];
        sc[6] = (float)s67[0]; sc[7] = (float)s67[1];
        #pragma unroll
        for (int s = 0; s < 8; ++s)
            if (s > tpos) sc[s] = -1.0e30f;

        float m = sc[0];
        #pragma unroll
        for (int s = 1; s < 8; ++s) m = fmaxf(m, sc[s]);
        float e[8], sum = 0.f;
        #pragma unroll
        for (int s = 0; s < 8; ++s) { e[s] = __expf(sc[s] - m); sum += e[s]; }
        const float winv = 1.0f / sum;

        // packed softmax weights (winv folded in)
        uint32_t wp[4];
        wp[0] = pk(e[0] * winv, e[1] * winv);
        wp[1] = pk(e[2] * winv, e[3] * winv);
        wp[2] = pk(e[4] * winv, e[5] * winv);
        wp[3] = pk(e[6] * winv, e[7] * winv);
        const h16x2 w0 = bch(wp[0]), w1 = bch(wp[1]), w2 = bch(wp[2]), w3 = bch(wp[3]);

        // PV: o[d] = sum_s w[s] * V_T[gg*8+d][s]  (even/odd partial sums in f16,
        // horizontal-combined in f32)
        float o[8];
        #pragma unroll
        for (int d = 0; d < 8; ++d) {
            const uint4 vu = *(const uint4*)(vb + (((d << 2) | gg) * 32) + bb * 16);
            h16x2 acc = w0 * bch(vu.x);
            acc += w1 * bch(vu.y);
            acc += w2 * bch(vu.z);
            acc += w3 * bch(vu.w);
            o[d] = (float)acc[0] + (float)acc[1];
        }

        // ---- FF: A-frag from o (row=cc, k=gg*8+j) — R3-proven mapping ----
        F8U aO;
        aO.u[0] = pk(o[0], o[1]);
        aO.u[1] = pk(o[2], o[3]);
        aO.u[2] = pk(o[4], o[5]);
        aO.u[3] = pk(o[6], o[7]);

        const f32x4 y0 = __builtin_amdgcn_mfma_f32_16x16x32_f16(aO.v, bF[0], z, 0, 0, 0);
        const f32x4 y1 = __builtin_amdgcn_mfma_f32_16x16x32_f16(aO.v, bF[1], z, 0, 0, 0);

        // ---- bias + ReLU in C-frag layout, direct global stores (R3-exact) ----
        #pragma unroll
        for (int r = 0; r < 4; ++r) {
            float* yp = Y + (size_t)(rowbase + gg * 4 + r) * C_;
            yp[cc]      = fmaxf(y0[r] + bias0, 0.f);
            yp[cc + 16] = fmaxf(y1[r] + bias1, 0.f);
        }
    }
}

extern "C" void kernel_launch(void* const* d_in, const int* in_sizes, int n_in,
                              void* d_out, int out_size, void* d_ws, size_t ws_size,
                              hipStream_t stream)
{
    const float* X  = (const float*)d_in[0];
    const float* Wq = (const float*)d_in[1];
    const float* Wk = (const float*)d_in[2];
    const float* Wv = (const float*)d_in[3];
    const float* Wf = (const float*)d_in[4];
    const float* bf = (const float*)d_in[5];
    float* Y = (float*)d_out;

    const int rows = B_ * T_;                           // 1,048,576
    const int rows_per_block = 4 * TILES_PER_WAVE * 16; // 256
    dim3 grid(rows / rows_per_block), block(256);
    hipLaunchKernelGGL(attn_block_mfma, grid, block, 0, stream,
                       X, Wq, Wk, Wv, Wf, bf, Y);
}

// Round 9
// 52.549 us; speedup vs baseline: 1.7426x; 1.3955x over previous
//
#include <hip/hip_runtime.h>
#include <stdint.h>

// Problem constants
#define B_ 131072
#define T_ 8
#define C_ 32
#define H_ 4
#define D_ 8

#define NT 4      // tiles per wave
// per-wave HALF-slab: Q f32 [16 rows][36 dw] = 2304 B;
//                     K_T f16 [32 rows][32 B] = 1024 B; V_T same = 1024 B
#define QOFF 0
#define KOFF 2304
#define VOFF 3328
#define HSLAB 4352           // one buffer
// double-buffered: 2*HSLAB per wave -> 34816 B/block -> 4 blocks/CU

typedef _Float16 h16x2 __attribute__((ext_vector_type(2)));
typedef _Float16 f16x8 __attribute__((ext_vector_type(8)));
typedef float    f32x4 __attribute__((ext_vector_type(4)));
typedef __fp16   fp16x2 __attribute__((ext_vector_type(2)));  // cvt_pkrtz ret

union H2U { fp16x2 h; uint32_t u; };
union HW  { uint32_t u; h16x2 h; };
union F8U { f16x8 v; uint32_t u[4]; };

__device__ inline uint32_t pk(float lo, float hi) {
    H2U t; t.h = __builtin_amdgcn_cvt_pkrtz(lo, hi); return t.u;
}
__device__ inline h16x2 bch(uint32_t x) { HW t; t.u = x; return t.h; }

struct X2 { float4 a, b; };

// One wave = 16 rows (2 causal batches of T=8) per tile, NT tiles, fully
// software-pipelined: stage(it+1) [QKV MFMA + LDS writes, slab (it+1)&1]
// issues BEFORE attn(it) [slab it&1], hiding LDS write latency under
// attention VALU. K/V stored feature-major f16 with bijective row permute
// p(f)=((f&3)<<3)|(f>>2): write banks (cc>>2)*8+gg*2 cover all 32 banks
// (4-deep b64 = floor); reads are broadcast/2-way. LDS wave-private.
__global__ __launch_bounds__(256, 4) void attn_block_mfma(
    const float* __restrict__ X,
    const float* __restrict__ Wq,
    const float* __restrict__ Wk,
    const float* __restrict__ Wv,
    const float* __restrict__ Wf,
    const float* __restrict__ bfb,
    float* __restrict__ Y)
{
    __shared__ __align__(16) char ldsraw[4][2][HSLAB];
    const int wid  = threadIdx.x >> 6;
    const int lane = threadIdx.x & 63;
    const int cc = lane & 15;   // C-frag col; attention row t
    const int gg = lane >> 4;   // k-group; attention head
    char* base = &ldsraw[wid][0][0];

    const float qscale = 0.35355339059327373f;  // 1/sqrt(D), folded into Wq

    // ---------- preamble: weight B-frags (f16) ----------
    f16x8 bW[6];   // 0,1=q  2,3=k  4,5=v   (B-frag: col=lane&15, k=gg*8+j)
    {
        const float* const Ws[3] = { Wq, Wk, Wv };
        #pragma unroll
        for (int tau = 0; tau < 6; ++tau) {
            const float* Wm = Ws[tau >> 1];
            const int col = (tau & 1) * 16 + cc;
            const int head = col >> 3, d = col & 7;
            #pragma unroll
            for (int j = 0; j < 8; ++j) {
                float f = Wm[head * (C_ * D_) + (gg * 8 + j) * D_ + d];
                if (tau < 2) f *= qscale;
                bW[tau][j] = (_Float16)f;
            }
        }
    }
    f16x8 bF[2];   // FF weights
    {
        #pragma unroll
        for (int tau = 0; tau < 2; ++tau) {
            const int col = tau * 16 + cc;
            #pragma unroll
            for (int j = 0; j < 8; ++j)
                bF[tau][j] = (_Float16)Wf[(gg * 8 + j) * C_ + col];
        }
    }
    const float bias0 = bfb[cc];
    const float bias1 = bfb[cc + 16];

    const int tilebase = (blockIdx.x * 4 + wid) * (16 * NT);
    const f32x4 z = { 0.f, 0.f, 0.f, 0.f };

    auto ldx = [&](int it) {
        const float* p = X + (size_t)(tilebase + it * 16 + cc) * C_ + gg * 8;
        X2 r; r.a = *(const float4*)p; r.b = *(const float4*)(p + 4); return r;
    };

    // stage: QKV projection for one tile into slab `slot`
    auto stage = [&](int slot, X2 x) {
        f16x8 aX;   // A-frag from X: row = lane&15, k = gg*8+j
        aX[0] = (_Float16)x.a.x; aX[1] = (_Float16)x.a.y;
        aX[2] = (_Float16)x.a.z; aX[3] = (_Float16)x.a.w;
        aX[4] = (_Float16)x.b.x; aX[5] = (_Float16)x.b.y;
        aX[6] = (_Float16)x.b.z; aX[7] = (_Float16)x.b.w;

        f32x4 cq[6];
        #pragma unroll
        for (int tau = 0; tau < 6; ++tau)
            cq[tau] = __builtin_amdgcn_mfma_f32_16x16x32_f16(aX, bW[tau], z, 0, 0, 0);

        char* b2 = base + slot * HSLAB;
        float* qb = (float*)(b2 + QOFF);
        // Q -> f32, stride 36 dw (2-way banks, free)
        #pragma unroll
        for (int tau = 0; tau < 2; ++tau)
            #pragma unroll
            for (int r = 0; r < 4; ++r)
                qb[(gg * 4 + r) * 36 + tau * 16 + cc] = cq[tau][r];
        // K,V -> packed f16 feature-major; row p(f) = ((f&3)<<3)|(f>>2),
        // f = (tau&1)*16+cc  ->  p = (cc&3)*8 + (tau&1)*4 + (cc>>2)
        #pragma unroll
        for (int tau = 2; tau < 6; ++tau) {
            char* dst = b2 + ((tau < 4) ? KOFF : VOFF);
            const int p = (cc & 3) * 8 + (tau & 1) * 4 + (cc >> 2);
            uint2 w2;
            w2.x = pk(cq[tau][0], cq[tau][1]);
            w2.y = pk(cq[tau][2], cq[tau][3]);
            *(uint2*)(dst + p * 32 + gg * 8) = w2;
        }
    };

    // attn + FF + store for one tile from slab `slot`
    auto attn = [&](int slot, int it) {
        char* b2 = base + slot * HSLAB;
        const float* qb = (const float*)(b2 + QOFF);
        const char*  kb = b2 + KOFF;
        const char*  vb = b2 + VOFF;
        const int tpos = cc & 7, bb = cc >> 3;

        const float4 qa = *(const float4*)(qb + cc * 36 + gg * 8);
        const float4 qv = *(const float4*)(qb + cc * 36 + gg * 8 + 4);
        uint32_t qp[8];
        qp[0] = pk(qa.x, qa.x); qp[1] = pk(qa.y, qa.y);
        qp[2] = pk(qa.z, qa.z); qp[3] = pk(qa.w, qa.w);
        qp[4] = pk(qv.x, qv.x); qp[5] = pk(qv.y, qv.y);
        qp[6] = pk(qv.z, qv.z); qp[7] = pk(qv.w, qv.w);

        // scores: K_T row for f = gg*8+j is p = ((j&3)<<3)|(gg*2)|(j>>2);
        // 8 distinct addrs/inst, broadcast over cc&7 lanes
        h16x2 s01 = { (_Float16)0, (_Float16)0 };
        h16x2 s23 = s01, s45 = s01, s67 = s01;
        #pragma unroll
        for (int j = 0; j < 8; ++j) {
            const int p = ((j & 3) << 3) | (gg * 2) | (j >> 2);
            const uint4 ku = *(const uint4*)(kb + p * 32 + bb * 16);
            const h16x2 qj = bch(qp[j]);
            s01 += qj * bch(ku.x);
            s23 += qj * bch(ku.y);
            s45 += qj * bch(ku.z);
            s67 += qj * bch(ku.w);
        }
        float sc[8];
        sc[0] = (float)s01[0]; sc[1] = (float)s01[1];
        sc[2] = (float)s23[0]; sc[3] = (float)s23[1];
        sc[4] = (float)s45[0]; sc[5] = (float)s45[1];
        sc[6] = (float)s67[0]; sc[7] = (float)s67[1];
        #pragma unroll
        for (int s = 0; s < 8; ++s)
            if (s > tpos) sc[s] = -1.0e30f;

        float m = sc[0];
        #pragma unroll
        for (int s = 1; s < 8; ++s) m = fmaxf(m, sc[s]);
        float e[8], sum = 0.f;
        #pragma unroll
        for (int s = 0; s < 8; ++s) { e[s] = __expf(sc[s] - m); sum += e[s]; }
        const float winv = 1.0f / sum;

        uint32_t wp[4];
        wp[0] = pk(e[0] * winv, e[1] * winv);
        wp[1] = pk(e[2] * winv, e[3] * winv);
        wp[2] = pk(e[4] * winv, e[5] * winv);
        wp[3] = pk(e[6] * winv, e[7] * winv);
        const h16x2 w0 = bch(wp[0]), w1 = bch(wp[1]);
        const h16x2 w2 = bch(wp[2]), w3 = bch(wp[3]);

        float o[8];
        #pragma unroll
        for (int d = 0; d < 8; ++d) {
            const int p = ((d & 3) << 3) | (gg * 2) | (d >> 2);
            const uint4 vu = *(const uint4*)(vb + p * 32 + bb * 16);
            h16x2 acc = w0 * bch(vu.x);
            acc += w1 * bch(vu.y);
            acc += w2 * bch(vu.z);
            acc += w3 * bch(vu.w);
            o[d] = (float)acc[0] + (float)acc[1];
        }

        // FF: A-frag from o (row=cc, k=gg*8+j)
        F8U aO;
        aO.u[0] = pk(o[0], o[1]);
        aO.u[1] = pk(o[2], o[3]);
        aO.u[2] = pk(o[4], o[5]);
        aO.u[3] = pk(o[6], o[7]);

        const f32x4 y0 = __builtin_amdgcn_mfma_f32_16x16x32_f16(aO.v, bF[0], z, 0, 0, 0);
        const f32x4 y1 = __builtin_amdgcn_mfma_f32_16x16x32_f16(aO.v, bF[1], z, 0, 0, 0);

        const int rowbase = tilebase + it * 16;
        #pragma unroll
        for (int r = 0; r < 4; ++r) {
            float* yp = Y + (size_t)(rowbase + gg * 4 + r) * C_;
            yp[cc]      = fmaxf(y0[r] + bias0, 0.f);
            yp[cc + 16] = fmaxf(y1[r] + bias1, 0.f);
        }
    };

    // ---- explicit software pipeline (NT = 4) ----
    X2 x0 = ldx(0), x1 = ldx(1), x2 = ldx(2);
    stage(0, x0);
    X2 x3 = ldx(3);
    stage(1, x1);
    attn(0, 0);
    stage(0, x2);
    attn(1, 1);
    stage(1, x3);
    attn(0, 2);
    attn(1, 3);
}

extern "C" void kernel_launch(void* const* d_in, const int* in_sizes, int n_in,
                              void* d_out, int out_size, void* d_ws, size_t ws_size,
                              hipStream_t stream)
{
    const float* X  = (const float*)d_in[0];
    const float* Wq = (const float*)d_in[1];
    const float* Wk = (const float*)d_in[2];
    const float* Wv = (const float*)d_in[3];
    const float* Wf = (const float*)d_in[4];
    const float* bf = (const float*)d_in[5];
    float* Y = (float*)d_out;

    const int rows = B_ * T_;                 // 1,048,576
    const int rows_per_block = 4 * NT * 16;   // 256
    dim3 grid(rows / rows_per_block), block(256);
    hipLaunchKernelGGL(attn_block_mfma, grid, block, 0, stream,
                       X, Wq, Wk, Wv, Wf, bf, Y);
}